// Round 19
// baseline (130.529 us; speedup 1.0000x reference)
//
#include <hip/hip_runtime.h>
#include <hip/hip_fp16.h>
#include <cstdint>
#include <cstddef>

#define Bc 4
#define Dd 192
#define Hh 192
#define Ww 192
#define KK 25
#define RR 12          // K//2
#define VOL (Bc*Dd*Hh*Ww)   // 28,311,552
#define SP 216         // u16 row stride of P (12 halo + 192 + 12 halo)
#define SPU (SP/2)     // 108 u32
#define SH 98          // u16 LDS row stride for d tiles
#define RIN 88         // staged rows per wh block (64 out + 2*12 halo)
#define RD  56         // staged rows per d block

typedef unsigned short u16;
typedef unsigned int   u32;
typedef __fp16 h2 __attribute__((ext_vector_type(2)));
typedef __fp16 h8 __attribute__((ext_vector_type(8)));
typedef float  f32x4 __attribute__((ext_vector_type(4)));

__device__ inline u32 pk2(float a, float b) {
    return __builtin_bit_cast(u32, __builtin_amdgcn_cvt_pkrtz(a, b));
}

// Compute normalized truncated-Gaussian tap `idx` (0..24) for sigma01 value.
__device__ inline float gauss_tap(float s01, int idx) {
    float sig = s01 * 3.0f;                 // MAX_SIGMA
    float s = fmaxf(sig, 1e-3f);
    float inv2 = -0.5f / (s * s);
    float sum = 0.0f;
    #pragma unroll
    for (int i = 0; i < KK; i++) {
        float a = (float)(i - RR);
        sum += __expf(a * a * inv2);
    }
    float a = (float)(idx - RR);
    float v = __expf(a * a * inv2) / sum;
    if (sig < 0.01f) v = (idx == RR) ? 1.0f : 0.0f;   // delta
    return v;
}

// ---------------------------------------------------------------------------
// Kernel 1: FUSED bias*exp + W-blur (MFMA banded, IN PLACE) + H-blur (pk_fma)
// + label remap on DEDICATED waves 6-7 (overlaps the MFMA phase).
// 64-out-row tile per 512-thread block (88 staged). LDS 40164 B -> 4 blocks/CU
// x 8 waves = 32 waves/CU (full occupancy).
// ---------------------------------------------------------------------------
__global__ __launch_bounds__(512) void pass_wh_remap_kernel(
    const float* __restrict__ x, u16* __restrict__ outB,
    const float* __restrict__ sigma01, const float* __restrict__ sb,
    const int* __restrict__ src, const int* __restrict__ dst,
    const int4* __restrict__ labels, float4* __restrict__ lab_out) {
    __shared__ __attribute__((aligned(16))) u16 P[RIN * SP];   // 38016 B
    __shared__ __attribute__((aligned(16))) float ch[RIN][4];  // 1408 B
    __shared__ u16 kpadW[64];                            // zero-guarded W taps
    __shared__ u32 khp[25];                              // H taps (packed dup)
    __shared__ float Lmap[128];                          // label LUT
    const int tid = threadIdx.x;
    const int hx = blockIdx.x;          // third: output rows [64hx, 64hx+64)
    const int d  = blockIdx.y;
    const int b  = blockIdx.z;

    // --- phase 0: bias node coeffs + per-block tap tables + Lmap init ---
    if (tid < RIN) {
        int r = tid;
        int hrow = min(max(64 * hx - RR + r, 0), Hh - 1);
        float pos_d = d * (3.0f / 191.0f);
        int   id0   = min((int)pos_d, 2);
        float fd    = pos_d - (float)id0;
        float pos_h = hrow * (3.0f / 191.0f);
        int   ih0   = min((int)pos_h, 2);
        float fh    = pos_h - (float)ih0;
        const float* sbA = sb + b * 64 + id0 * 16 + ih0 * 4;
        #pragma unroll
        for (int k = 0; k < 4; k++) {
            float v00 = sbA[k],      v01 = sbA[4 + k];
            float v10 = sbA[16 + k], v11 = sbA[20 + k];
            float vd0 = (1.f - fd) * v00 + fd * v10;
            float vd1 = (1.f - fd) * v01 + fd * v11;
            ch[r][k] = ((1.f - fh) * vd0 + fh * vd1) * 0.7f;
        }
    }
    if (tid >= 96 && tid < 224) Lmap[tid - 96] = 0.0f;
    if (tid >= 224 && tid < 249) {        // H taps (axis b*3+1)
        int i = tid - 224;
        float v = gauss_tap(sigma01[b * 3 + 1], i);
        u16 hb = __builtin_bit_cast(u16, __float2half(v));
        khp[i] = (u32)hb | ((u32)hb << 16);
    }
    if (tid >= 256 && tid < 320) {        // W taps, zero-guarded (axis b*3+2)
        int i = tid - 256;                // kpadW[i] = tap(i-15), 0 outside
        int tt = i - 15;
        u16 v = 0;
        if (tt >= 0 && tt < KK)
            v = __builtin_bit_cast(u16, __float2half(gauss_tap(sigma01[b * 3 + 2], tt)));
        kpadW[i] = v;
    }
    __syncthreads();

    // Lmap scatter (after zero-init barrier; consumed after phase-1 barrier)
    if (tid < 32) {
        int s = src[tid];
        if (s >= 0 && s < 128) Lmap[s] = (float)dst[tid];
    }

    // --- phase 1: fixed-w threads iterate rows. 480 active threads:
    //     w4 = tid%48 (position math once), rows = it*10 + tid/48, 9 iters. ---
    const size_t pbase = ((size_t)b * Dd + d) * (size_t)(Hh * Ww);
    {
        const int w4 = tid % 48;
        const int rloc = tid / 48;            // 0..10 (active: 0..9)
        const int w = 4 * w4;
        float fwj[4];
        bool  s1j[4], s2j[4];
        #pragma unroll
        for (int j = 0; j < 4; j++) {
            float pw = (float)(w + j) * (3.0f / 191.0f);
            bool s1 = pw >= 1.0f, s2 = pw >= 2.0f;
            s1j[j] = s1; s2j[j] = s2;
            float fb = s2 ? 2.0f : (s1 ? 1.0f : 0.0f);
            fwj[j] = pw - fb;
        }
        #pragma unroll
        for (int it = 0; it < 9; it++) {
            int row = it * 10 + rloc;
            if (rloc < 10 && row < RIN) {
                int hrow = min(max(64 * hx - RR + row, 0), Hh - 1);
                float4 v = *(const float4*)(x + pbase + (size_t)hrow * Ww + w);
                float4 cv = *(const float4*)&ch[row][0];
                float rs[4];
                #pragma unroll
                for (int j = 0; j < 4; j++) {
                    float clo = s2j[j] ? cv.z : (s1j[j] ? cv.y : cv.x);
                    float chi = s2j[j] ? cv.w : (s1j[j] ? cv.z : cv.y);
                    float bias = fmaf(fwj[j], chi - clo, clo);
                    float val = (j == 0 ? v.x : j == 1 ? v.y : j == 2 ? v.z : v.w);
                    rs[j] = val * __expf(bias);
                }
                u32* dstp = (u32*)&P[row * SP + RR + w];
                dstp[0] = pk2(rs[0], rs[1]);
                dstp[1] = pk2(rs[2], rs[3]);
                if (w4 == 0) {                // left replicate halo (w=0)
                    u32 hh = pk2(rs[0], rs[0]);
                    u32* hp = (u32*)&P[row * SP];
                    #pragma unroll
                    for (int m = 0; m < 6; m++) hp[m] = hh;
                } else if (w4 == 47) {        // right replicate halo (w=191)
                    u32 hh = pk2(rs[3], rs[3]);
                    u32* hp = (u32*)&P[row * SP + RR + Ww];
                    #pragma unroll
                    for (int m = 0; m < 6; m++) hp[m] = hh;
                }
            }
        }
    }
    __syncthreads();

    // --- phase 2, wave-specialized:
    //     waves 0-5: W-blur via MFMA 16x16x32 f16, banded taps, IN PLACE.
    //       Wave wv owns rows [16wv, min(16wv+16, 88)); A-frags register-
    //       staged BEFORE writes; batch load regions disjoint from preceding
    //       writes; all offsets in-row (G12/13 kg==0 only).
    //     waves 6-7: stream this block's 3072 int4 label slice (load/map/
    //       store in 4 chunks) -- HBM latency absorbed inside MFMA window. ---
    {
        const int wv = tid >> 6;
        if (wv < 6) {
            const int ln = tid & 63;
            const int c  = ln & 15;            // A-row sel / D-col / B-col
            const int kg = ln >> 4;            // k-group 0..3 (k = kg*8+j)
            h8 B0, B1;
            #pragma unroll
            for (int j = 0; j < 8; j++) {
                int k = kg * 8 + j;
                B0[j] = __builtin_bit_cast(__fp16, kpadW[15 + k - c]);
                int i1 = 15 + k + 32 - c;      // >=64 for kg>0 -> tap 0
                B1[j] = __builtin_bit_cast(__fp16, (i1 < 64) ? kpadW[i1] : (u16)0);
            }
            const int ra = min(wv * 16 + c, RIN - 1);     // A row (clamped)
            const u16* rowp = &P[ra * SP + kg * 8];
            const int rd0 = wv * 16 + kg * 4;             // D base row
            h8 F[10];
            #pragma unroll
            for (int f = 0; f < 10; f++)
                F[f] = __builtin_bit_cast(h8, *(const uint4*)(rowp + f * 16));
            #pragma unroll
            for (int ct = 0; ct < 8; ct++) {
                f32x4 acc = {0.f, 0.f, 0.f, 0.f};
                acc = __builtin_amdgcn_mfma_f32_16x16x32_f16(F[ct], B0, acc, 0, 0, 0);
                acc = __builtin_amdgcn_mfma_f32_16x16x32_f16(F[ct + 2], B1, acc, 0, 0, 0);
                #pragma unroll
                for (int m = 0; m < 4; m++) {
                    int rd = rd0 + m;
                    if (rd < RIN)
                        P[rd * SP + RR + ct * 16 + c] =
                            __builtin_bit_cast(u16, (__fp16)acc[m]);
                }
            }
            h8 G[4];
            G[0] = __builtin_bit_cast(h8, *(const uint4*)(rowp + 160));
            G[1] = __builtin_bit_cast(h8, *(const uint4*)(rowp + 176));
            G[2] = __builtin_bit_cast(h8, *(const uint4*)(rowp + ((kg == 0) ? 192 : 160)));
            G[3] = __builtin_bit_cast(h8, *(const uint4*)(rowp + ((kg == 0) ? 208 : 160)));
            #pragma unroll
            for (int ct = 8; ct < 12; ct++) {
                h8 A0 = (ct < 10) ? F[ct] : G[ct - 10];
                h8 A1 = G[ct - 8];
                f32x4 acc = {0.f, 0.f, 0.f, 0.f};
                acc = __builtin_amdgcn_mfma_f32_16x16x32_f16(A0, B0, acc, 0, 0, 0);
                acc = __builtin_amdgcn_mfma_f32_16x16x32_f16(A1, B1, acc, 0, 0, 0);
                #pragma unroll
                for (int m = 0; m < 4; m++) {
                    int rd = rd0 + m;
                    if (rd < RIN)
                        P[rd * SP + RR + ct * 16 + c] =
                            __builtin_bit_cast(u16, (__fp16)acc[m]);
                }
            }
        } else {
            // label-streaming waves (128 threads x 24 int4, 4 chunks of 6)
            const int idx = tid - 384;
            const int bid = (b * Dd + d) * 3 + hx;        // 0..2303
            const size_t base = (size_t)bid * 3072 + idx;
            #pragma unroll
            for (int chk = 0; chk < 4; chk++) {
                int4 lab[6];
                #pragma unroll
                for (int m = 0; m < 6; m++)
                    lab[m] = labels[base + (size_t)(chk * 6 + m) * 128];
                #pragma unroll
                for (int m = 0; m < 6; m++) {
                    int4 l = lab[m];
                    float4 o;
                    o.x = Lmap[min(max(l.x, 0), 127)];
                    o.y = Lmap[min(max(l.y, 0), 127)];
                    o.z = Lmap[min(max(l.z, 0), 127)];
                    o.w = Lmap[min(max(l.w, 0), 127)];
                    lab_out[base + (size_t)(chk * 6 + m) * 128] = o;
                }
            }
        }
    }
    __syncthreads();

    // --- phase 3: H-blur (pk_fma on P columns, 8-row groups), write out.
    //     768 items over 512 threads (it0 full, it1 half). ---
    {
        u32 khr[KK];
        #pragma unroll
        for (int t = 0; t < KK; t++) khr[t] = khp[t];
        u32* outp = (u32*)(outB + pbase);
        #pragma unroll
        for (int it = 0; it < 2; it++) {
            int item = it * 512 + tid;        // need < 768
            if (item < 768) {
                int col = item % 96;          // u32 column (2 w)
                int g = item / 96;            // 0..7 (8-row output group)
                u32 win[32];
                #pragma unroll
                for (int i = 0; i < 32; i++)
                    win[i] = *((const u32*)P + (g * 8 + i) * SPU + 6 + col);
                h2 acc[8];
                #pragma unroll
                for (int j = 0; j < 8; j++) acc[j] = (h2)(0.0f);
                #pragma unroll
                for (int t = 0; t < KK; t++) {
                    h2 kv = __builtin_bit_cast(h2, khr[t]);
                    #pragma unroll
                    for (int j = 0; j < 8; j++)
                        acc[j] += kv * __builtin_bit_cast(h2, win[j + t]);
                }
                #pragma unroll
                for (int j = 0; j < 8; j++)
                    outp[(64 * hx + g * 8 + j) * 96 + col] =
                        __builtin_bit_cast(u32, acc[j]);
            }
        }
    }
}

// ---------------------------------------------------------------------------
// Kernel 2: D-blur, f16 -> f32 final. Block 192, tile 32d x 96w at (b,h).
// Builds its own D taps per block (no setup kernel).
// ---------------------------------------------------------------------------
__global__ __launch_bounds__(192) void pass_d_kernel(
    const u16* __restrict__ in, float* __restrict__ img,
    const float* __restrict__ sigma01) {
    __shared__ __attribute__((aligned(16))) u16 T[RD * SH];   // 10976 B
    __shared__ u32 kdp[25];
    const int tid = threadIdx.x;
    const int w0 = blockIdx.x * 96;
    const int d0 = blockIdx.y * 32;
    const int z = blockIdx.z;
    const int h = z % Hh, b = z / Hh;
    if (tid < 25) {                       // D taps (axis b*3+0)
        float v = gauss_tap(sigma01[b * 3 + 0], tid);
        u16 hb = __builtin_bit_cast(u16, __float2half(v));
        kdp[tid] = (u32)hb | ((u32)hb << 16);
    }
    #pragma unroll
    for (int k = 0; k < 4; k++) {
        int idx = k * 192 + tid;
        if (idx < RD * 12) {
            int r = idx / 12, sg = idx % 12;
            int dd = min(max(d0 + r - RR, 0), Dd - 1);
            uint4 v = *(const uint4*)(in + (((size_t)b * Dd + dd) * Hh + h) * (size_t)Ww + w0 + sg * 8);
            u32* p = (u32*)&T[r * SH + sg * 8];
            p[0] = v.x; p[1] = v.y; p[2] = v.z; p[3] = v.w;
        }
    }
    __syncthreads();
    u32 kdr[KK];
    #pragma unroll
    for (int t = 0; t < KK; t++) kdr[t] = kdp[t];
    const int p = tid % 48;
    const int g = tid / 48;               // 0..3 -> output rows 8g..8g+7
    const int ob = g * 8;
    u32 win[32];
    #pragma unroll
    for (int i = 0; i < 32; i++) win[i] = *(const u32*)&T[(ob + i) * SH + 2 * p];
    h2 acc[8];
    #pragma unroll
    for (int j = 0; j < 8; j++) acc[j] = (h2)(0.0f);
    #pragma unroll
    for (int t = 0; t < KK; t++) {
        h2 kv = __builtin_bit_cast(h2, kdr[t]);
        #pragma unroll
        for (int j = 0; j < 8; j++)
            acc[j] += kv * __builtin_bit_cast(h2, win[j + t]);
    }
    #pragma unroll
    for (int j = 0; j < 8; j++) {
        h2 a = acc[j];
        float2 f = make_float2((float)a.x, (float)a.y);
        *(float2*)(img + (((size_t)b * Dd + (d0 + ob + j)) * Hh + h) * (size_t)Ww + w0 + 2 * p) = f;
    }
}

extern "C" void kernel_launch(void* const* d_in, const int* in_sizes, int n_in,
                              void* d_out, int out_size, void* d_ws, size_t ws_size,
                              hipStream_t stream) {
    const float* x          = (const float*)d_in[0];
    const float* small_bias = (const float*)d_in[1];
    const float* sigma01    = (const float*)d_in[2];
    const int*   labels     = (const int*)d_in[3];
    const int*   src        = (const int*)d_in[4];
    const int*   dst        = (const int*)d_in[5];

    float* out     = (float*)d_out;
    float* img     = out;                   // first VOL f32
    float* lab_out = out + (size_t)VOL;     // second VOL f32
    u16*   Bb      = (u16*)((char*)d_ws + 8192);      // f16 volume, VOL elems

    // fused bias*exp + W(MFMA in-place) + H + wave-specialized remap
    pass_wh_remap_kernel<<<dim3(3, Dd, Bc), 512, 0, stream>>>(
        x, Bb, sigma01, small_bias, src, dst,
        (const int4*)labels, (float4*)lab_out);
    // D-blur: Bb -> img (f32 final)
    pass_d_kernel<<<dim3(Ww / 96, Dd / 32, Bc * Hh), 192, 0, stream>>>(
        Bb, img, sigma01);
}

// Round 20
// 128.436 us; speedup vs baseline: 1.0163x; 1.0163x over previous
//
#include <hip/hip_runtime.h>
#include <hip/hip_fp16.h>
#include <cstdint>
#include <cstddef>

#define Bc 4
#define Dd 192
#define Hh 192
#define Ww 192
#define KK 25
#define RR 12          // K//2
#define VOL (Bc*Dd*Hh*Ww)   // 28,311,552
#define SP 216         // u16 row stride of P (12 halo + 192 + 12 halo)
#define SPU (SP/2)     // 108 u32
#define SH 98          // u16 LDS row stride for d tiles
#define RIN 56         // staged rows per wh block (32 out + 2*12 halo)
#define RD  56         // staged rows per d block

typedef unsigned short u16;
typedef unsigned int   u32;
typedef __fp16 h2 __attribute__((ext_vector_type(2)));
typedef __fp16 h8 __attribute__((ext_vector_type(8)));
typedef float  f32x4 __attribute__((ext_vector_type(4)));

__device__ inline u32 pk2(float a, float b) {
    return __builtin_bit_cast(u32, __builtin_amdgcn_cvt_pkrtz(a, b));
}

// Compute normalized truncated-Gaussian tap `idx` (0..24) for sigma01 value.
__device__ inline float gauss_tap(float s01, int idx) {
    float sig = s01 * 3.0f;                 // MAX_SIGMA
    float s = fmaxf(sig, 1e-3f);
    float inv2 = -0.5f / (s * s);
    float sum = 0.0f;
    #pragma unroll
    for (int i = 0; i < KK; i++) {
        float a = (float)(i - RR);
        sum += __expf(a * a * inv2);
    }
    float a = (float)(idx - RR);
    float v = __expf(a * a * inv2) / sum;
    if (sig < 0.01f) v = (idx == RR) ? 1.0f : 0.0f;   // delta
    return v;
}

// ---------------------------------------------------------------------------
// Kernel 1: FUSED bias*exp + W-blur (MFMA banded, IN PLACE) + H-blur (pk_fma,
// 8-row groups) + streamed label remap. Self-contained taps/LUT. 32-out-row
// tile, 256 threads, LDS ~26.3 KB -> 6 blocks/CU. launch_bounds(256,6):
// VGPR cap ~85 so the register-staged MFMA A-frags (F[10]+G[4]) don't spill.
// ---------------------------------------------------------------------------
__global__ __launch_bounds__(256, 6) void pass_wh_remap_kernel(
    const float* __restrict__ x, u16* __restrict__ outB,
    const float* __restrict__ sigma01, const float* __restrict__ sb,
    const int* __restrict__ src, const int* __restrict__ dst,
    const int4* __restrict__ labels, float4* __restrict__ lab_out) {
    __shared__ u16 P[RIN * SP];                          // 24192 B
    __shared__ float2 ch2[RIN * 3];                      // 1344 B
    __shared__ u16 kpadW[64];                            // zero-guarded W taps
    __shared__ u32 khp[25];                              // H taps (packed dup)
    __shared__ float Lmap[128];                          // label LUT
    const int tid = threadIdx.x;
    const int hx = blockIdx.x;          // sixth: output rows [32hx, 32hx+32)
    const int d  = blockIdx.y;
    const int b  = blockIdx.z;

    // --- phase 0: bias coeff pairs + per-block tap tables + Lmap init ---
    if (tid < RIN) {
        int r = tid;
        int hrow = min(max(32 * hx - RR + r, 0), Hh - 1);
        float pos_d = d * (3.0f / 191.0f);
        int   id0   = min((int)pos_d, 2);
        float fd    = pos_d - (float)id0;
        float pos_h = hrow * (3.0f / 191.0f);
        int   ih0   = min((int)pos_h, 2);
        float fh    = pos_h - (float)ih0;
        const float* sbA = sb + b * 64 + id0 * 16 + ih0 * 4;
        float c[4];
        #pragma unroll
        for (int k = 0; k < 4; k++) {
            float v00 = sbA[k],      v01 = sbA[4 + k];
            float v10 = sbA[16 + k], v11 = sbA[20 + k];
            float vd0 = (1.f - fd) * v00 + fd * v10;
            float vd1 = (1.f - fd) * v01 + fd * v11;
            c[k] = ((1.f - fh) * vd0 + fh * vd1) * 0.7f;
        }
        #pragma unroll
        for (int k = 0; k < 3; k++)
            ch2[r * 3 + k] = make_float2(c[k], c[k + 1] - c[k]);
    }
    if (tid >= 56 && tid < 184) Lmap[tid - 56] = 0.0f;
    if (tid >= 56 && tid < 81) {          // H taps (axis b*3+1)
        int i = tid - 56;
        float v = gauss_tap(sigma01[b * 3 + 1], i);
        u16 hb = __builtin_bit_cast(u16, __float2half(v));
        khp[i] = (u32)hb | ((u32)hb << 16);
    }
    if (tid >= 184 && tid < 248) {        // W taps, zero-guarded (axis b*3+2)
        int i = tid - 184;                // kpadW[i] = tap(i-15), 0 outside
        int tt = i - 15;
        u16 v = 0;
        if (tt >= 0 && tt < KK)
            v = __builtin_bit_cast(u16, __float2half(gauss_tap(sigma01[b * 3 + 2], tt)));
        kpadW[i] = v;
    }
    __syncthreads();

    // Lmap scatter (after init barrier; done before phase-1's end barrier)
    if (tid < 32) {
        int s = src[tid];
        if (s >= 0 && s < 128) Lmap[s] = (float)dst[tid];
    }

    // --- phase 1: fixed-w threads iterate rows. 240 active threads:
    //     w4 = tid%48 (position math computed ONCE), rows = it*5 + tid/48. ---
    const size_t pbase = ((size_t)b * Dd + d) * (size_t)(Hh * Ww);
    {
        const int w4 = tid % 48;
        const int rloc = tid / 48;            // 0..5 (active: 0..4)
        const int w = 4 * w4;
        float fwj[4];
        int   selj[4];
        #pragma unroll
        for (int j = 0; j < 4; j++) {
            float pw = (float)(w + j) * (3.0f / 191.0f);
            int sel = (pw >= 1.0f) + (pw >= 2.0f);
            selj[j] = sel;
            fwj[j] = pw - (float)sel;
        }
        #pragma unroll
        for (int it = 0; it < 12; it++) {
            int row = it * 5 + rloc;
            if (tid < 240 && row < RIN) {
                int hrow = min(max(32 * hx - RR + row, 0), Hh - 1);
                float4 v = *(const float4*)(x + pbase + (size_t)hrow * Ww + w);
                float rs[4];
                #pragma unroll
                for (int j = 0; j < 4; j++) {
                    float2 cd = ch2[row * 3 + selj[j]];
                    float bias = fmaf(fwj[j], cd.y, cd.x);
                    float val = (j == 0 ? v.x : j == 1 ? v.y : j == 2 ? v.z : v.w);
                    rs[j] = val * __expf(bias);
                }
                u32* dstp = (u32*)&P[row * SP + RR + w];
                dstp[0] = pk2(rs[0], rs[1]);
                dstp[1] = pk2(rs[2], rs[3]);
                if (w4 == 0) {                // left replicate halo (w=0)
                    u32 hh = pk2(rs[0], rs[0]);
                    u32* hp = (u32*)&P[row * SP];
                    #pragma unroll
                    for (int m = 0; m < 6; m++) hp[m] = hh;
                } else if (w4 == 47) {        // right replicate halo (w=191)
                    u32 hh = pk2(rs[3], rs[3]);
                    u32* hp = (u32*)&P[row * SP + RR + Ww];
                    #pragma unroll
                    for (int m = 0; m < 6; m++) hp[m] = hh;
                }
            }
        }
    }
    __syncthreads();

    // --- label stream: loads issued while mem pipe idles; stores drain
    //     under the compute phases ---
    {
        const int bid = (b * Dd + d) * 6 + hx;        // 0..4607
        const int4* lp = labels + (size_t)bid * 1536 + tid;
        int4 lab[6];
        #pragma unroll
        for (int m = 0; m < 6; m++) lab[m] = lp[m * 256];
        float4* op = lab_out + (size_t)bid * 1536 + tid;
        #pragma unroll
        for (int m = 0; m < 6; m++) {
            int4 l = lab[m];
            float4 o;
            o.x = Lmap[min(max(l.x, 0), 127)];
            o.y = Lmap[min(max(l.y, 0), 127)];
            o.z = Lmap[min(max(l.z, 0), 127)];
            o.w = Lmap[min(max(l.w, 0), 127)];
            op[m * 256] = o;
        }
    }

    // --- phase 2: W-blur via MFMA 16x16x32 f16, banded taps, IN PLACE.
    //     Wave wv owns rows [16wv, 16wv+16) (wave 3 clamped to 48..55).
    //     A-frags register-staged BEFORE writes; batch load regions disjoint
    //     from preceding writes; all offsets in-row (G12/13 kg==0 only). ---
    {
        const int ln = tid & 63, wv = tid >> 6;
        const int c  = ln & 15;            // A-row sel / D-col / B-col
        const int kg = ln >> 4;            // k-group 0..3 (k = kg*8+j)
        h8 B0, B1;
        #pragma unroll
        for (int j = 0; j < 8; j++) {
            int k = kg * 8 + j;
            B0[j] = __builtin_bit_cast(__fp16, kpadW[15 + k - c]);
            int i1 = 15 + k + 32 - c;      // >=64 for kg>0 -> tap 0
            B1[j] = __builtin_bit_cast(__fp16, (i1 < 64) ? kpadW[i1] : (u16)0);
        }
        const int ra = min(wv * 16 + c, RIN - 1);     // A row (clamped)
        const u16* rowp = &P[ra * SP + kg * 8];
        const int rd0 = wv * 16 + kg * 4;             // D base row
        h8 F[10];
        #pragma unroll
        for (int f = 0; f < 10; f++)
            F[f] = __builtin_bit_cast(h8, *(const uint4*)(rowp + f * 16));
        #pragma unroll
        for (int ct = 0; ct < 8; ct++) {
            f32x4 acc = {0.f, 0.f, 0.f, 0.f};
            acc = __builtin_amdgcn_mfma_f32_16x16x32_f16(F[ct], B0, acc, 0, 0, 0);
            acc = __builtin_amdgcn_mfma_f32_16x16x32_f16(F[ct + 2], B1, acc, 0, 0, 0);
            #pragma unroll
            for (int m = 0; m < 4; m++) {
                int rd = rd0 + m;
                if (rd < RIN)
                    P[rd * SP + RR + ct * 16 + c] =
                        __builtin_bit_cast(u16, (__fp16)acc[m]);
            }
        }
        h8 G[4];
        G[0] = __builtin_bit_cast(h8, *(const uint4*)(rowp + 160));
        G[1] = __builtin_bit_cast(h8, *(const uint4*)(rowp + 176));
        G[2] = __builtin_bit_cast(h8, *(const uint4*)(rowp + ((kg == 0) ? 192 : 160)));
        G[3] = __builtin_bit_cast(h8, *(const uint4*)(rowp + ((kg == 0) ? 208 : 160)));
        #pragma unroll
        for (int ct = 8; ct < 12; ct++) {
            h8 A0 = (ct < 10) ? F[ct] : G[ct - 10];
            h8 A1 = G[ct - 8];
            f32x4 acc = {0.f, 0.f, 0.f, 0.f};
            acc = __builtin_amdgcn_mfma_f32_16x16x32_f16(A0, B0, acc, 0, 0, 0);
            acc = __builtin_amdgcn_mfma_f32_16x16x32_f16(A1, B1, acc, 0, 0, 0);
            #pragma unroll
            for (int m = 0; m < 4; m++) {
                int rd = rd0 + m;
                if (rd < RIN)
                    P[rd * SP + RR + ct * 16 + c] =
                        __builtin_bit_cast(u16, (__fp16)acc[m]);
            }
        }
    }
    __syncthreads();

    // --- phase 3: H-blur (pk_fma on P columns, 8-row groups), write out ---
    {
        u32 khr[KK];
        #pragma unroll
        for (int t = 0; t < KK; t++) khr[t] = khp[t];
        u32* outp = (u32*)(outB + pbase);
        #pragma unroll
        for (int it = 0; it < 2; it++) {
            int item = it * 256 + tid;        // 0..511, need < 384
            if (item < 384) {
                int col = item % 96;          // u32 column (2 w)
                int g = item / 96;            // 0..3 (8-row output group)
                u32 win[32];
                #pragma unroll
                for (int i = 0; i < 32; i++)
                    win[i] = *((const u32*)P + (g * 8 + i) * SPU + 6 + col);
                h2 acc[8];
                #pragma unroll
                for (int j = 0; j < 8; j++) acc[j] = (h2)(0.0f);
                #pragma unroll
                for (int t = 0; t < KK; t++) {
                    h2 kv = __builtin_bit_cast(h2, khr[t]);
                    #pragma unroll
                    for (int j = 0; j < 8; j++)
                        acc[j] += kv * __builtin_bit_cast(h2, win[j + t]);
                }
                #pragma unroll
                for (int j = 0; j < 8; j++)
                    outp[(32 * hx + g * 8 + j) * 96 + col] =
                        __builtin_bit_cast(u32, acc[j]);
            }
        }
    }
}

// ---------------------------------------------------------------------------
// Kernel 2: D-blur, f16 -> f32 final. Block 192, tile 32d x 96w at (b,h).
// Builds its own D taps per block (no setup kernel).
// ---------------------------------------------------------------------------
__global__ __launch_bounds__(192) void pass_d_kernel(
    const u16* __restrict__ in, float* __restrict__ img,
    const float* __restrict__ sigma01) {
    __shared__ __attribute__((aligned(16))) u16 T[RD * SH];   // 10976 B
    __shared__ u32 kdp[25];
    const int tid = threadIdx.x;
    const int w0 = blockIdx.x * 96;
    const int d0 = blockIdx.y * 32;
    const int z = blockIdx.z;
    const int h = z % Hh, b = z / Hh;
    if (tid < 25) {                       // D taps (axis b*3+0)
        float v = gauss_tap(sigma01[b * 3 + 0], tid);
        u16 hb = __builtin_bit_cast(u16, __float2half(v));
        kdp[tid] = (u32)hb | ((u32)hb << 16);
    }
    #pragma unroll
    for (int k = 0; k < 4; k++) {
        int idx = k * 192 + tid;
        if (idx < RD * 12) {
            int r = idx / 12, sg = idx % 12;
            int dd = min(max(d0 + r - RR, 0), Dd - 1);
            uint4 v = *(const uint4*)(in + (((size_t)b * Dd + dd) * Hh + h) * (size_t)Ww + w0 + sg * 8);
            u32* p = (u32*)&T[r * SH + sg * 8];
            p[0] = v.x; p[1] = v.y; p[2] = v.z; p[3] = v.w;
        }
    }
    __syncthreads();
    u32 kdr[KK];
    #pragma unroll
    for (int t = 0; t < KK; t++) kdr[t] = kdp[t];
    const int p = tid % 48;
    const int g = tid / 48;               // 0..3 -> output rows 8g..8g+7
    const int ob = g * 8;
    u32 win[32];
    #pragma unroll
    for (int i = 0; i < 32; i++) win[i] = *(const u32*)&T[(ob + i) * SH + 2 * p];
    h2 acc[8];
    #pragma unroll
    for (int j = 0; j < 8; j++) acc[j] = (h2)(0.0f);
    #pragma unroll
    for (int t = 0; t < KK; t++) {
        h2 kv = __builtin_bit_cast(h2, kdr[t]);
        #pragma unroll
        for (int j = 0; j < 8; j++)
            acc[j] += kv * __builtin_bit_cast(h2, win[j + t]);
    }
    #pragma unroll
    for (int j = 0; j < 8; j++) {
        h2 a = acc[j];
        float2 f = make_float2((float)a.x, (float)a.y);
        *(float2*)(img + (((size_t)b * Dd + (d0 + ob + j)) * Hh + h) * (size_t)Ww + w0 + 2 * p) = f;
    }
}

extern "C" void kernel_launch(void* const* d_in, const int* in_sizes, int n_in,
                              void* d_out, int out_size, void* d_ws, size_t ws_size,
                              hipStream_t stream) {
    const float* x          = (const float*)d_in[0];
    const float* small_bias = (const float*)d_in[1];
    const float* sigma01    = (const float*)d_in[2];
    const int*   labels     = (const int*)d_in[3];
    const int*   src        = (const int*)d_in[4];
    const int*   dst        = (const int*)d_in[5];

    float* out     = (float*)d_out;
    float* img     = out;                   // first VOL f32
    float* lab_out = out + (size_t)VOL;     // second VOL f32
    u16*   Bb      = (u16*)((char*)d_ws + 8192);      // f16 volume, VOL elems

    // fused bias*exp + W(MFMA in-place) + H + streamed remap (self-contained)
    pass_wh_remap_kernel<<<dim3(6, Dd, Bc), 256, 0, stream>>>(
        x, Bb, sigma01, small_bias, src, dst,
        (const int4*)labels, (float4*)lab_out);
    // D-blur: Bb -> img (f32 final)
    pass_d_kernel<<<dim3(Ww / 96, Dd / 32, Bc * Hh), 192, 0, stream>>>(
        Bb, img, sigma01);
}

// Round 21
// 127.235 us; speedup vs baseline: 1.0259x; 1.0094x over previous
//
#include <hip/hip_runtime.h>
#include <hip/hip_fp16.h>
#include <cstdint>
#include <cstddef>

#define Bc 4
#define Dd 192
#define Hh 192
#define Ww 192
#define KK 25
#define RR 12          // K//2
#define VOL (Bc*Dd*Hh*Ww)   // 28,311,552
#define SP 216         // u16 row stride of P (12 halo + 192 + 12 halo)
#define SPU (SP/2)     // 108 u32
#define SH 98          // u16 LDS row stride for d tiles
#define RIN 56         // staged rows per wh block (32 out + 2*12 halo)
#define RD  56         // staged rows per d block

typedef unsigned short u16;
typedef unsigned int   u32;
typedef __fp16 h2 __attribute__((ext_vector_type(2)));
typedef __fp16 h8 __attribute__((ext_vector_type(8)));
typedef float  f32x4 __attribute__((ext_vector_type(4)));

__device__ inline u32 pk2(float a, float b) {
    return __builtin_bit_cast(u32, __builtin_amdgcn_cvt_pkrtz(a, b));
}

// Compute normalized truncated-Gaussian tap `idx` (0..24) for sigma01 value.
__device__ inline float gauss_tap(float s01, int idx) {
    float sig = s01 * 3.0f;                 // MAX_SIGMA
    float s = fmaxf(sig, 1e-3f);
    float inv2 = -0.5f / (s * s);
    float sum = 0.0f;
    #pragma unroll
    for (int i = 0; i < KK; i++) {
        float a = (float)(i - RR);
        sum += __expf(a * a * inv2);
    }
    float a = (float)(idx - RR);
    float v = __expf(a * a * inv2) / sum;
    if (sig < 0.01f) v = (idx == RR) ? 1.0f : 0.0f;   // delta
    return v;
}

// ---------------------------------------------------------------------------
// Kernel 1: FUSED bias*exp + W-blur (MFMA banded, IN PLACE) + H-blur (pk_fma,
// 8-row groups) + streamed label remap. Self-contained taps/LUT. 32-out-row
// tile, 256 threads, LDS ~26.3 KB -> 6 blocks/CU. Phase 1 uses 6-deep
// register-batched loads for MLP (explicit float4 arrays).
// ---------------------------------------------------------------------------
__global__ __launch_bounds__(256, 6) void pass_wh_remap_kernel(
    const float* __restrict__ x, u16* __restrict__ outB,
    const float* __restrict__ sigma01, const float* __restrict__ sb,
    const int* __restrict__ src, const int* __restrict__ dst,
    const int4* __restrict__ labels, float4* __restrict__ lab_out) {
    __shared__ u16 P[RIN * SP];                          // 24192 B
    __shared__ float2 ch2[RIN * 3];                      // 1344 B
    __shared__ u16 kpadW[64];                            // zero-guarded W taps
    __shared__ u32 khp[25];                              // H taps (packed dup)
    __shared__ float Lmap[128];                          // label LUT
    const int tid = threadIdx.x;
    const int hx = blockIdx.x;          // sixth: output rows [32hx, 32hx+32)
    const int d  = blockIdx.y;
    const int b  = blockIdx.z;

    // --- phase 0: bias coeff pairs + per-block tap tables + Lmap init ---
    if (tid < RIN) {
        int r = tid;
        int hrow = min(max(32 * hx - RR + r, 0), Hh - 1);
        float pos_d = d * (3.0f / 191.0f);
        int   id0   = min((int)pos_d, 2);
        float fd    = pos_d - (float)id0;
        float pos_h = hrow * (3.0f / 191.0f);
        int   ih0   = min((int)pos_h, 2);
        float fh    = pos_h - (float)ih0;
        const float* sbA = sb + b * 64 + id0 * 16 + ih0 * 4;
        float c[4];
        #pragma unroll
        for (int k = 0; k < 4; k++) {
            float v00 = sbA[k],      v01 = sbA[4 + k];
            float v10 = sbA[16 + k], v11 = sbA[20 + k];
            float vd0 = (1.f - fd) * v00 + fd * v10;
            float vd1 = (1.f - fd) * v01 + fd * v11;
            c[k] = ((1.f - fh) * vd0 + fh * vd1) * 0.7f;
        }
        #pragma unroll
        for (int k = 0; k < 3; k++)
            ch2[r * 3 + k] = make_float2(c[k], c[k + 1] - c[k]);
    }
    if (tid >= 56 && tid < 184) Lmap[tid - 56] = 0.0f;
    if (tid >= 56 && tid < 81) {          // H taps (axis b*3+1)
        int i = tid - 56;
        float v = gauss_tap(sigma01[b * 3 + 1], i);
        u16 hb = __builtin_bit_cast(u16, __float2half(v));
        khp[i] = (u32)hb | ((u32)hb << 16);
    }
    if (tid >= 184 && tid < 248) {        // W taps, zero-guarded (axis b*3+2)
        int i = tid - 184;                // kpadW[i] = tap(i-15), 0 outside
        int tt = i - 15;
        u16 v = 0;
        if (tt >= 0 && tt < KK)
            v = __builtin_bit_cast(u16, __float2half(gauss_tap(sigma01[b * 3 + 2], tt)));
        kpadW[i] = v;
    }
    __syncthreads();

    // Lmap scatter (after init barrier; done before phase-1's end barrier)
    if (tid < 32) {
        int s = src[tid];
        if (s >= 0 && s < 128) Lmap[s] = (float)dst[tid];
    }

    // --- phase 1: fixed-w threads iterate rows; TWO 6-row register batches
    //     (24 VGPR each) so 6 loads are in flight while computing. ---
    const size_t pbase = ((size_t)b * Dd + d) * (size_t)(Hh * Ww);
    {
        const int w4 = tid % 48;
        const int rloc = tid / 48;            // 0..5 (active: 0..4)
        const int w = 4 * w4;
        const bool act = (tid < 240);
        float fwj[4];
        int   selj[4];
        #pragma unroll
        for (int j = 0; j < 4; j++) {
            float pw = (float)(w + j) * (3.0f / 191.0f);
            int sel = (pw >= 1.0f) + (pw >= 2.0f);
            selj[j] = sel;
            fwj[j] = pw - (float)sel;
        }
        // rows handled by this thread: row(it) = it*5 + rloc, it = 0..11
        float4 vA[6], vB[6];
        #pragma unroll
        for (int it = 0; it < 6; it++) {      // batch A loads (rows it*5+rloc)
            int row = it * 5 + rloc;
            int hrow = min(max(32 * hx - RR + row, 0), Hh - 1);
            if (act && row < RIN)
                vA[it] = *(const float4*)(x + pbase + (size_t)hrow * Ww + w);
        }
        #pragma unroll
        for (int it = 0; it < 6; it++) {      // batch B loads (rows 30+..)
            int row = (it + 6) * 5 + rloc;
            int hrow = min(max(32 * hx - RR + row, 0), Hh - 1);
            if (act && row < RIN)
                vB[it] = *(const float4*)(x + pbase + (size_t)hrow * Ww + w);
        }
        #pragma unroll
        for (int half = 0; half < 2; half++) {
            #pragma unroll
            for (int it = 0; it < 6; it++) {
                int row = (half * 6 + it) * 5 + rloc;
                if (act && row < RIN) {
                    float4 v = half ? vB[it] : vA[it];
                    float rs[4];
                    #pragma unroll
                    for (int j = 0; j < 4; j++) {
                        float2 cd = ch2[row * 3 + selj[j]];
                        float bias = fmaf(fwj[j], cd.y, cd.x);
                        float val = (j == 0 ? v.x : j == 1 ? v.y : j == 2 ? v.z : v.w);
                        rs[j] = val * __expf(bias);
                    }
                    u32* dstp = (u32*)&P[row * SP + RR + w];
                    dstp[0] = pk2(rs[0], rs[1]);
                    dstp[1] = pk2(rs[2], rs[3]);
                    if (w4 == 0) {                // left replicate halo (w=0)
                        u32 hh = pk2(rs[0], rs[0]);
                        u32* hp = (u32*)&P[row * SP];
                        #pragma unroll
                        for (int m = 0; m < 6; m++) hp[m] = hh;
                    } else if (w4 == 47) {        // right replicate halo
                        u32 hh = pk2(rs[3], rs[3]);
                        u32* hp = (u32*)&P[row * SP + RR + Ww];
                        #pragma unroll
                        for (int m = 0; m < 6; m++) hp[m] = hh;
                    }
                }
            }
        }
    }
    __syncthreads();

    // --- label stream: loads issued while mem pipe idles; stores drain
    //     under the compute phases ---
    {
        const int bid = (b * Dd + d) * 6 + hx;        // 0..4607
        const int4* lp = labels + (size_t)bid * 1536 + tid;
        int4 lab[6];
        #pragma unroll
        for (int m = 0; m < 6; m++) lab[m] = lp[m * 256];
        float4* op = lab_out + (size_t)bid * 1536 + tid;
        #pragma unroll
        for (int m = 0; m < 6; m++) {
            int4 l = lab[m];
            float4 o;
            o.x = Lmap[min(max(l.x, 0), 127)];
            o.y = Lmap[min(max(l.y, 0), 127)];
            o.z = Lmap[min(max(l.z, 0), 127)];
            o.w = Lmap[min(max(l.w, 0), 127)];
            op[m * 256] = o;
        }
    }

    // --- phase 2: W-blur via MFMA 16x16x32 f16, banded taps, IN PLACE.
    //     Wave wv owns rows [16wv, 16wv+16) (wave 3 clamped to 48..55).
    //     A-frags register-staged BEFORE writes; batch load regions disjoint
    //     from preceding writes; all offsets in-row (G12/13 kg==0 only). ---
    {
        const int ln = tid & 63, wv = tid >> 6;
        const int c  = ln & 15;            // A-row sel / D-col / B-col
        const int kg = ln >> 4;            // k-group 0..3 (k = kg*8+j)
        h8 B0, B1;
        #pragma unroll
        for (int j = 0; j < 8; j++) {
            int k = kg * 8 + j;
            B0[j] = __builtin_bit_cast(__fp16, kpadW[15 + k - c]);
            int i1 = 15 + k + 32 - c;      // >=64 for kg>0 -> tap 0
            B1[j] = __builtin_bit_cast(__fp16, (i1 < 64) ? kpadW[i1] : (u16)0);
        }
        const int ra = min(wv * 16 + c, RIN - 1);     // A row (clamped)
        const u16* rowp = &P[ra * SP + kg * 8];
        const int rd0 = wv * 16 + kg * 4;             // D base row
        h8 F[10];
        #pragma unroll
        for (int f = 0; f < 10; f++)
            F[f] = __builtin_bit_cast(h8, *(const uint4*)(rowp + f * 16));
        #pragma unroll
        for (int ct = 0; ct < 8; ct++) {
            f32x4 acc = {0.f, 0.f, 0.f, 0.f};
            acc = __builtin_amdgcn_mfma_f32_16x16x32_f16(F[ct], B0, acc, 0, 0, 0);
            acc = __builtin_amdgcn_mfma_f32_16x16x32_f16(F[ct + 2], B1, acc, 0, 0, 0);
            #pragma unroll
            for (int m = 0; m < 4; m++) {
                int rd = rd0 + m;
                if (rd < RIN)
                    P[rd * SP + RR + ct * 16 + c] =
                        __builtin_bit_cast(u16, (__fp16)acc[m]);
            }
        }
        h8 G[4];
        G[0] = __builtin_bit_cast(h8, *(const uint4*)(rowp + 160));
        G[1] = __builtin_bit_cast(h8, *(const uint4*)(rowp + 176));
        G[2] = __builtin_bit_cast(h8, *(const uint4*)(rowp + ((kg == 0) ? 192 : 160)));
        G[3] = __builtin_bit_cast(h8, *(const uint4*)(rowp + ((kg == 0) ? 208 : 160)));
        #pragma unroll
        for (int ct = 8; ct < 12; ct++) {
            h8 A0 = (ct < 10) ? F[ct] : G[ct - 10];
            h8 A1 = G[ct - 8];
            f32x4 acc = {0.f, 0.f, 0.f, 0.f};
            acc = __builtin_amdgcn_mfma_f32_16x16x32_f16(A0, B0, acc, 0, 0, 0);
            acc = __builtin_amdgcn_mfma_f32_16x16x32_f16(A1, B1, acc, 0, 0, 0);
            #pragma unroll
            for (int m = 0; m < 4; m++) {
                int rd = rd0 + m;
                if (rd < RIN)
                    P[rd * SP + RR + ct * 16 + c] =
                        __builtin_bit_cast(u16, (__fp16)acc[m]);
            }
        }
    }
    __syncthreads();

    // --- phase 3: H-blur (pk_fma on P columns, 8-row groups), write out ---
    {
        u32 khr[KK];
        #pragma unroll
        for (int t = 0; t < KK; t++) khr[t] = khp[t];
        u32* outp = (u32*)(outB + pbase);
        #pragma unroll
        for (int it = 0; it < 2; it++) {
            int item = it * 256 + tid;        // 0..511, need < 384
            if (item < 384) {
                int col = item % 96;          // u32 column (2 w)
                int g = item / 96;            // 0..3 (8-row output group)
                u32 win[32];
                #pragma unroll
                for (int i = 0; i < 32; i++)
                    win[i] = *((const u32*)P + (g * 8 + i) * SPU + 6 + col);
                h2 acc[8];
                #pragma unroll
                for (int j = 0; j < 8; j++) acc[j] = (h2)(0.0f);
                #pragma unroll
                for (int t = 0; t < KK; t++) {
                    h2 kv = __builtin_bit_cast(h2, khr[t]);
                    #pragma unroll
                    for (int j = 0; j < 8; j++)
                        acc[j] += kv * __builtin_bit_cast(h2, win[j + t]);
                }
                #pragma unroll
                for (int j = 0; j < 8; j++)
                    outp[(32 * hx + g * 8 + j) * 96 + col] =
                        __builtin_bit_cast(u32, acc[j]);
            }
        }
    }
}

// ---------------------------------------------------------------------------
// Kernel 2: D-blur, f16 -> f32 final. Block 192, tile 32d x 96w at (b,h).
// Builds its own D taps per block (no setup kernel).
// ---------------------------------------------------------------------------
__global__ __launch_bounds__(192) void pass_d_kernel(
    const u16* __restrict__ in, float* __restrict__ img,
    const float* __restrict__ sigma01) {
    __shared__ __attribute__((aligned(16))) u16 T[RD * SH];   // 10976 B
    __shared__ u32 kdp[25];
    const int tid = threadIdx.x;
    const int w0 = blockIdx.x * 96;
    const int d0 = blockIdx.y * 32;
    const int z = blockIdx.z;
    const int h = z % Hh, b = z / Hh;
    if (tid < 25) {                       // D taps (axis b*3+0)
        float v = gauss_tap(sigma01[b * 3 + 0], tid);
        u16 hb = __builtin_bit_cast(u16, __float2half(v));
        kdp[tid] = (u32)hb | ((u32)hb << 16);
    }
    #pragma unroll
    for (int k = 0; k < 4; k++) {
        int idx = k * 192 + tid;
        if (idx < RD * 12) {
            int r = idx / 12, sg = idx % 12;
            int dd = min(max(d0 + r - RR, 0), Dd - 1);
            uint4 v = *(const uint4*)(in + (((size_t)b * Dd + dd) * Hh + h) * (size_t)Ww + w0 + sg * 8);
            u32* p = (u32*)&T[r * SH + sg * 8];
            p[0] = v.x; p[1] = v.y; p[2] = v.z; p[3] = v.w;
        }
    }
    __syncthreads();
    u32 kdr[KK];
    #pragma unroll
    for (int t = 0; t < KK; t++) kdr[t] = kdp[t];
    const int p = tid % 48;
    const int g = tid / 48;               // 0..3 -> output rows 8g..8g+7
    const int ob = g * 8;
    u32 win[32];
    #pragma unroll
    for (int i = 0; i < 32; i++) win[i] = *(const u32*)&T[(ob + i) * SH + 2 * p];
    h2 acc[8];
    #pragma unroll
    for (int j = 0; j < 8; j++) acc[j] = (h2)(0.0f);
    #pragma unroll
    for (int t = 0; t < KK; t++) {
        h2 kv = __builtin_bit_cast(h2, kdr[t]);
        #pragma unroll
        for (int j = 0; j < 8; j++)
            acc[j] += kv * __builtin_bit_cast(h2, win[j + t]);
    }
    #pragma unroll
    for (int j = 0; j < 8; j++) {
        h2 a = acc[j];
        float2 f = make_float2((float)a.x, (float)a.y);
        *(float2*)(img + (((size_t)b * Dd + (d0 + ob + j)) * Hh + h) * (size_t)Ww + w0 + 2 * p) = f;
    }
}

extern "C" void kernel_launch(void* const* d_in, const int* in_sizes, int n_in,
                              void* d_out, int out_size, void* d_ws, size_t ws_size,
                              hipStream_t stream) {
    const float* x          = (const float*)d_in[0];
    const float* small_bias = (const float*)d_in[1];
    const float* sigma01    = (const float*)d_in[2];
    const int*   labels     = (const int*)d_in[3];
    const int*   src        = (const int*)d_in[4];
    const int*   dst        = (const int*)d_in[5];

    float* out     = (float*)d_out;
    float* img     = out;                   // first VOL f32
    float* lab_out = out + (size_t)VOL;     // second VOL f32
    u16*   Bb      = (u16*)((char*)d_ws + 8192);      // f16 volume, VOL elems

    // fused bias*exp + W(MFMA in-place) + H + streamed remap (self-contained)
    pass_wh_remap_kernel<<<dim3(6, Dd, Bc), 256, 0, stream>>>(
        x, Bb, sigma01, small_bias, src, dst,
        (const int4*)labels, (float4*)lab_out);
    // D-blur: Bb -> img (f32 final)
    pass_d_kernel<<<dim3(Ww / 96, Dd / 32, Bc * Hh), 192, 0, stream>>>(
        Bb, img, sigma01);
}